// Round 1
// baseline (464.766 us; speedup 1.0000x reference)
//
#include <hip/hip_runtime.h>
#include <math.h>

typedef __bf16 bf16;
typedef __attribute__((ext_vector_type(8))) __bf16 bf16x8;
typedef __attribute__((ext_vector_type(4))) __bf16 bf16x4;
typedef __attribute__((ext_vector_type(4))) float f32x4;

#define NTOK 4096
#define DM   1024
#define NE   8
#define HE   704
#define HS   1408

// ---------------- workspace layout (bytes) ----------------
#define OFF_CNT   0u            // 8 ints, pfx[9] at +32
#define OFF_TOK   256u          // 8*4096 ints
#define OFF_WGT   131328u       // 8*4096 floats
#define OFF_XB    262400u       // 4096*1024 bf16
#define OFF_W1T   8651008u      // [E][HE][DM] bf16
#define OFF_W3T   20185344u
#define OFF_W2T   31719680u     // [E][DM][HE] bf16
#define OFF_WS1T  43254016u     // [HS][DM] bf16
#define OFF_WS3T  46137600u
#define OFF_WS2T  49021184u     // [DM][HS] bf16
#define OFF_ACTR  51904768u     // [8192][HE] bf16 (compacted by prefix sum)
#define OFF_ACTS  63439104u     // [NTOK][HS] bf16
// end: 74973440 (~71.5 MB)

// ---------------- x -> bf16 ----------------
__global__ void cvt_x_kernel(const float* __restrict__ x, bf16* __restrict__ xb, int n4)
{
    int i = blockIdx.x * blockDim.x + threadIdx.x;
    if (i >= n4) return;
    float4 v = ((const float4*)x)[i];
    bf16x4 o;
    o[0] = (bf16)v.x; o[1] = (bf16)v.y; o[2] = (bf16)v.z; o[3] = (bf16)v.w;
    ((bf16x4*)xb)[i] = o;
}

// ---------------- transpose + convert: src [R][C] f32 -> dst [C][R] bf16 ----------------
__global__ void transpose_cvt(const float* __restrict__ src, bf16* __restrict__ dst, int R, int C)
{
    __shared__ float t[32][33];
    int c0 = blockIdx.x * 32, r0 = blockIdx.y * 32;
    size_t base = (size_t)blockIdx.z * (size_t)R * (size_t)C;
    src += base; dst += base;
    int row  = threadIdx.x >> 3;        // 0..31
    int col4 = (threadIdx.x & 7) * 4;   // 0..28
    float4 v = *(const float4*)&src[(size_t)(r0 + row) * C + c0 + col4];
    t[row][col4 + 0] = v.x; t[row][col4 + 1] = v.y;
    t[row][col4 + 2] = v.z; t[row][col4 + 3] = v.w;
    __syncthreads();
    bf16x4 o;
    o[0] = (bf16)t[col4 + 0][row];
    o[1] = (bf16)t[col4 + 1][row];
    o[2] = (bf16)t[col4 + 2][row];
    o[3] = (bf16)t[col4 + 3][row];
    *(bf16x4*)&dst[(size_t)(c0 + row) * R + r0 + col4] = o;
}

// ---------------- router: fp32 logits, softmax, top-2, scatter ----------------
__global__ void router_kernel(const float* __restrict__ x, const float* __restrict__ Wg,
                              int* __restrict__ cnt, int* __restrict__ tok, float* __restrict__ wgt)
{
    int n = blockIdx.x;
    int lane = threadIdx.x;
    const float* xrow = x + (size_t)n * DM;
    float xr[16];
    #pragma unroll
    for (int j = 0; j < 16; j++) xr[j] = xrow[lane + 64 * j];
    float logit[NE];
    #pragma unroll
    for (int e = 0; e < NE; e++) {
        const float* wr = Wg + e * DM;
        float s = 0.f;
        #pragma unroll
        for (int j = 0; j < 16; j++) s += xr[j] * wr[lane + 64 * j];
        #pragma unroll
        for (int off = 32; off; off >>= 1) s += __shfl_xor(s, off, 64);
        logit[e] = s;
    }
    if (lane == 0) {
        int i0 = 0;
        #pragma unroll
        for (int e = 1; e < NE; e++) if (logit[e] > logit[i0]) i0 = e;
        int i1 = (i0 == 0) ? 1 : 0;
        #pragma unroll
        for (int e = 0; e < NE; e++) if (e != i0 && logit[e] > logit[i1]) i1 = e;
        float m = logit[0];
        #pragma unroll
        for (int e = 1; e < NE; e++) m = fmaxf(m, logit[e]);
        float denom = 0.f;
        #pragma unroll
        for (int e = 0; e < NE; e++) denom += expf(logit[e] - m);
        float g0 = expf(logit[i0] - m) / denom;
        float g1 = expf(logit[i1] - m) / denom;
        float inv = 1.f / (g0 + g1 + 1e-20f);
        float w0 = g0 * inv, w1 = g1 * inv;
        int p0 = atomicAdd(&cnt[i0], 1);
        tok[i0 * NTOK + p0] = n; wgt[i0 * NTOK + p0] = w0;
        int p1 = atomicAdd(&cnt[i1], 1);
        tok[i1 * NTOK + p1] = n; wgt[i1 * NTOK + p1] = w1;
    }
}

__global__ void prefix_kernel(const int* __restrict__ cnt, int* __restrict__ pfx)
{
    if (threadIdx.x == 0) {
        int s = 0;
        for (int e = 0; e < NE; e++) { pfx[e] = s; s += cnt[e]; }
        pfx[NE] = s;
    }
}

// ---------------- GEMM1: act = silu(A@W1) * (A@W3), bf16 out ----------------
// A rows gathered via tok list (or identity when tok==nullptr).
// W1t/W3t are [e][Hdim][DM] (n-major, k-contiguous).
__global__ __launch_bounds__(256) void gemm1_swiglu(
    const bf16* __restrict__ xb,
    const bf16* __restrict__ W1t, const bf16* __restrict__ W3t,
    bf16* __restrict__ act,
    const int* __restrict__ cnt, const int* __restrict__ pfx, const int* __restrict__ tok,
    int Hdim)
{
    int e = blockIdx.z;
    int count = cnt ? cnt[e] : NTOK;
    int m0 = blockIdx.y * 64;
    if (m0 >= count) return;
    int h0 = blockIdx.x * 64;
    int base = pfx ? pfx[e] : 0;
    const bf16* B1 = W1t + (size_t)e * Hdim * DM;
    const bf16* B3 = W3t + (size_t)e * Hdim * DM;
    const int* tlist = tok ? tok + e * NTOK : nullptr;

    __shared__ bf16 As[64][40];
    __shared__ bf16 Bs1[64][40];
    __shared__ bf16 Bs3[64][40];

    int tid  = threadIdx.x;
    int lrow = tid >> 2;          // 0..63
    int lcol = (tid & 3) * 8;     // 0,8,16,24

    int slot = m0 + lrow;
    int rowIdx;
    if (tlist) rowIdx = (slot < count) ? tlist[slot] : 0;
    else       rowIdx = (slot < count) ? slot : 0;
    const bf16* aPtr  = xb + (size_t)rowIdx * DM + lcol;
    const bf16* b1Ptr = B1 + (size_t)(h0 + lrow) * DM + lcol;
    const bf16* b3Ptr = B3 + (size_t)(h0 + lrow) * DM + lcol;

    int wv = tid >> 6, lane = tid & 63;
    int lm = lane & 15, lk = (lane >> 4) * 8;

    f32x4 acch[4], accg[4];
    #pragma unroll
    for (int c = 0; c < 4; c++) {
        acch[c] = (f32x4){0.f, 0.f, 0.f, 0.f};
        accg[c] = (f32x4){0.f, 0.f, 0.f, 0.f};
    }

    for (int k0 = 0; k0 < DM; k0 += 32) {
        *(uint4*)&As[lrow][lcol]  = *(const uint4*)(aPtr + k0);
        *(uint4*)&Bs1[lrow][lcol] = *(const uint4*)(b1Ptr + k0);
        *(uint4*)&Bs3[lrow][lcol] = *(const uint4*)(b3Ptr + k0);
        __syncthreads();
        bf16x8 af = *(const bf16x8*)&As[wv * 16 + lm][lk];
        #pragma unroll
        for (int c = 0; c < 4; c++) {
            bf16x8 b1f = *(const bf16x8*)&Bs1[c * 16 + lm][lk];
            bf16x8 b3f = *(const bf16x8*)&Bs3[c * 16 + lm][lk];
            acch[c] = __builtin_amdgcn_mfma_f32_16x16x32_bf16(af, b1f, acch[c], 0, 0, 0);
            accg[c] = __builtin_amdgcn_mfma_f32_16x16x32_bf16(af, b3f, accg[c], 0, 0, 0);
        }
        __syncthreads();
    }

    #pragma unroll
    for (int c = 0; c < 4; c++) {
        #pragma unroll
        for (int r = 0; r < 4; r++) {
            int row = wv * 16 + (lane >> 4) * 4 + r;   // slot-local (MFMA C/D: row=quad*4+reg)
            int s2 = m0 + row;
            if (s2 < count) {
                float hv = acch[c][r], gv = accg[c][r];
                float a = hv / (1.f + expf(-hv)) * gv;
                act[(size_t)(base + s2) * Hdim + h0 + c * 16 + lm] = (bf16)a;
            }
        }
    }
}

// ---------------- GEMM2: out = act @ W2 (+ gate, scatter) ----------------
// W2t is [e][DM][Hdim] (n-major, k-contiguous).
__global__ __launch_bounds__(256) void gemm2_combine(
    const bf16* __restrict__ act,
    const bf16* __restrict__ W2t,
    float* __restrict__ out,
    const int* __restrict__ cnt, const int* __restrict__ pfx,
    const int* __restrict__ tok, const float* __restrict__ wgt,
    int Hdim, int atomic_mode)
{
    int e = blockIdx.z;
    int count = cnt ? cnt[e] : NTOK;
    int m0 = blockIdx.y * 64;
    if (m0 >= count) return;
    int d0 = blockIdx.x * 64;
    int base = pfx ? pfx[e] : 0;
    const bf16* B = W2t + (size_t)e * DM * Hdim;

    __shared__ bf16 As[64][40];
    __shared__ bf16 Bs[64][40];

    int tid  = threadIdx.x;
    int lrow = tid >> 2;
    int lcol = (tid & 3) * 8;

    int slot = m0 + lrow;
    int arow = (slot < count) ? (base + slot) : base;   // clamp: garbage rows masked in epilogue
    const bf16* aPtr = act + (size_t)arow * Hdim + lcol;
    const bf16* bPtr = B + (size_t)(d0 + lrow) * Hdim + lcol;

    int wv = tid >> 6, lane = tid & 63;
    int lm = lane & 15, lk = (lane >> 4) * 8;

    f32x4 acc[4];
    #pragma unroll
    for (int c = 0; c < 4; c++) acc[c] = (f32x4){0.f, 0.f, 0.f, 0.f};

    for (int k0 = 0; k0 < Hdim; k0 += 32) {
        *(uint4*)&As[lrow][lcol] = *(const uint4*)(aPtr + k0);
        *(uint4*)&Bs[lrow][lcol] = *(const uint4*)(bPtr + k0);
        __syncthreads();
        bf16x8 af = *(const bf16x8*)&As[wv * 16 + lm][lk];
        #pragma unroll
        for (int c = 0; c < 4; c++) {
            bf16x8 bf_ = *(const bf16x8*)&Bs[c * 16 + lm][lk];
            acc[c] = __builtin_amdgcn_mfma_f32_16x16x32_bf16(af, bf_, acc[c], 0, 0, 0);
        }
        __syncthreads();
    }

    #pragma unroll
    for (int c = 0; c < 4; c++) {
        #pragma unroll
        for (int r = 0; r < 4; r++) {
            int row = wv * 16 + (lane >> 4) * 4 + r;
            int s2 = m0 + row;
            if (s2 < count) {
                int col = d0 + c * 16 + lm;
                float v = acc[c][r];
                if (atomic_mode) {
                    int t = tok[e * NTOK + s2];
                    float w = wgt[e * NTOK + s2];
                    atomicAdd(&out[(size_t)t * DM + col], w * v);
                } else {
                    out[(size_t)s2 * DM + col] = v;
                }
            }
        }
    }
}

extern "C" void kernel_launch(void* const* d_in, const int* in_sizes, int n_in,
                              void* d_out, int out_size, void* d_ws, size_t ws_size,
                              hipStream_t stream)
{
    const float* x   = (const float*)d_in[0];
    const float* Wg  = (const float*)d_in[1];
    const float* W1  = (const float*)d_in[2];
    const float* W3  = (const float*)d_in[3];
    const float* W2  = (const float*)d_in[4];
    const float* Ws1 = (const float*)d_in[5];
    const float* Ws3 = (const float*)d_in[6];
    const float* Ws2 = (const float*)d_in[7];
    float* out = (float*)d_out;
    char*  ws  = (char*)d_ws;

    int*   cnt  = (int*)(ws + OFF_CNT);
    int*   pfx  = (int*)(ws + OFF_CNT + 32);
    int*   tok  = (int*)(ws + OFF_TOK);
    float* wgt  = (float*)(ws + OFF_WGT);
    bf16*  xb   = (bf16*)(ws + OFF_XB);
    bf16*  w1t  = (bf16*)(ws + OFF_W1T);
    bf16*  w3t  = (bf16*)(ws + OFF_W3T);
    bf16*  w2t  = (bf16*)(ws + OFF_W2T);
    bf16*  ws1t = (bf16*)(ws + OFF_WS1T);
    bf16*  ws3t = (bf16*)(ws + OFF_WS3T);
    bf16*  ws2t = (bf16*)(ws + OFF_WS2T);
    bf16*  actr = (bf16*)(ws + OFF_ACTR);
    bf16*  acts = (bf16*)(ws + OFF_ACTS);

    hipMemsetAsync(ws, 0, 256, stream);

    cvt_x_kernel<<<4096, 256, 0, stream>>>(x, xb, NTOK * DM / 4);

    // weights -> bf16, transposed to [n][k]
    transpose_cvt<<<dim3(22, 32, 8), 256, 0, stream>>>(W1,  w1t,  1024, 704);
    transpose_cvt<<<dim3(22, 32, 8), 256, 0, stream>>>(W3,  w3t,  1024, 704);
    transpose_cvt<<<dim3(32, 22, 8), 256, 0, stream>>>(W2,  w2t,  704, 1024);
    transpose_cvt<<<dim3(44, 32, 1), 256, 0, stream>>>(Ws1, ws1t, 1024, 1408);
    transpose_cvt<<<dim3(44, 32, 1), 256, 0, stream>>>(Ws3, ws3t, 1024, 1408);
    transpose_cvt<<<dim3(32, 44, 1), 256, 0, stream>>>(Ws2, ws2t, 1408, 1024);

    router_kernel<<<4096, 64, 0, stream>>>(x, Wg, cnt, tok, wgt);
    prefix_kernel<<<1, 64, 0, stream>>>(cnt, pfx);

    // routed expert up-proj + swiglu
    gemm1_swiglu<<<dim3(HE / 64, 64, NE), 256, 0, stream>>>(xb, w1t, w3t, actr, cnt, pfx, tok, HE);
    // shared expert up-proj + swiglu
    gemm1_swiglu<<<dim3(HS / 64, 64, 1), 256, 0, stream>>>(xb, ws1t, ws3t, acts, nullptr, nullptr, nullptr, HS);
    // shared expert down-proj: dense write of out (covers every element)
    gemm2_combine<<<dim3(DM / 64, 64, 1), 256, 0, stream>>>(acts, ws2t, out, nullptr, nullptr, nullptr, nullptr, HS, 0);
    // routed down-proj: gate-weighted atomic accumulate on top
    gemm2_combine<<<dim3(DM / 64, 64, NE), 256, 0, stream>>>(actr, w2t, out, cnt, pfx, tok, wgt, HE, 1);
}

// Round 2
// 380.954 us; speedup vs baseline: 1.2200x; 1.2200x over previous
//
#include <hip/hip_runtime.h>
#include <math.h>

typedef __bf16 bf16;
typedef __attribute__((ext_vector_type(8))) __bf16 bf16x8;
typedef __attribute__((ext_vector_type(4))) __bf16 bf16x4;
typedef __attribute__((ext_vector_type(4))) float f32x4;

#define NTOK 4096
#define DM   1024
#define NE   8
#define HE   704
#define HS   1408

// ---------------- workspace layout (bytes) ----------------
#define OFF_CNT   0u            // 8 ints, pfx[9] at +32
#define OFF_TOK   256u          // 8*4096 ints
#define OFF_WGT   131328u       // 8*4096 floats
#define OFF_XB    262400u       // 4096*1024 bf16
#define OFF_W1T   8651008u      // [E][HE][DM] bf16
#define OFF_W3T   20185344u
#define OFF_W2T   31719680u     // [E][DM][HE] bf16
#define OFF_WS1T  43254016u     // [HS][DM] bf16
#define OFF_WS3T  46137600u
#define OFF_WS2T  49021184u     // [DM][HS] bf16
#define OFF_ACTR  51904768u     // [8192][HE] bf16 (compacted by prefix sum)
#define OFF_ACTS  63439104u     // [NTOK][HS] bf16
#define OFF_EIDS  74973440u     // [NTOK] int (e0 | e1<<16)
#define OFF_GW    74989824u     // [NTOK] float2 (w0, w1)
// end: 75022592 (~71.6 MB)

// ---------------- x -> bf16 ----------------
__global__ void cvt_x_kernel(const float* __restrict__ x, bf16* __restrict__ xb, int n4)
{
    int i = blockIdx.x * blockDim.x + threadIdx.x;
    if (i >= n4) return;
    float4 v = ((const float4*)x)[i];
    bf16x4 o;
    o[0] = (bf16)v.x; o[1] = (bf16)v.y; o[2] = (bf16)v.z; o[3] = (bf16)v.w;
    ((bf16x4*)xb)[i] = o;
}

// ---------------- transpose + convert: src [R][C] f32 -> dst [C][R] bf16 ----------------
__global__ void transpose_cvt(const float* __restrict__ src, bf16* __restrict__ dst, int R, int C)
{
    __shared__ float t[32][33];
    int c0 = blockIdx.x * 32, r0 = blockIdx.y * 32;
    size_t base = (size_t)blockIdx.z * (size_t)R * (size_t)C;
    src += base; dst += base;
    int row  = threadIdx.x >> 3;        // 0..31
    int col4 = (threadIdx.x & 7) * 4;   // 0..28
    float4 v = *(const float4*)&src[(size_t)(r0 + row) * C + c0 + col4];
    t[row][col4 + 0] = v.x; t[row][col4 + 1] = v.y;
    t[row][col4 + 2] = v.z; t[row][col4 + 3] = v.w;
    __syncthreads();
    bf16x4 o;
    o[0] = (bf16)t[col4 + 0][row];
    o[1] = (bf16)t[col4 + 1][row];
    o[2] = (bf16)t[col4 + 2][row];
    o[3] = (bf16)t[col4 + 3][row];
    *(bf16x4*)&dst[(size_t)(c0 + row) * R + r0 + col4] = o;
}

// ---------------- router pass 1: fp32 logits, softmax, top-2 per token (NO atomics) ----------------
__global__ __launch_bounds__(256) void router_logits(
    const float* __restrict__ x, const float* __restrict__ Wg,
    int* __restrict__ eids, float2* __restrict__ gw)
{
    int n    = blockIdx.x * 4 + (threadIdx.x >> 6);   // wave per token
    int lane = threadIdx.x & 63;
    const float* xrow = x + (size_t)n * DM;
    float xr[16];
    #pragma unroll
    for (int j = 0; j < 16; j++) xr[j] = xrow[lane + 64 * j];
    float logit[NE];
    #pragma unroll
    for (int e = 0; e < NE; e++) {
        const float* wr = Wg + e * DM;
        float s = 0.f;
        #pragma unroll
        for (int j = 0; j < 16; j++) s += xr[j] * wr[lane + 64 * j];
        #pragma unroll
        for (int off = 32; off; off >>= 1) s += __shfl_xor(s, off, 64);
        logit[e] = s;
    }
    if (lane == 0) {
        int i0 = 0;
        #pragma unroll
        for (int e = 1; e < NE; e++) if (logit[e] > logit[i0]) i0 = e;   // strict >: first-max wins (matches top_k tie rule)
        int i1 = (i0 == 0) ? 1 : 0;
        #pragma unroll
        for (int e = 0; e < NE; e++) if (e != i0 && logit[e] > logit[i1]) i1 = e;
        float m = logit[0];
        #pragma unroll
        for (int e = 1; e < NE; e++) m = fmaxf(m, logit[e]);
        float denom = 0.f;
        #pragma unroll
        for (int e = 0; e < NE; e++) denom += expf(logit[e] - m);
        float g0 = expf(logit[i0] - m) / denom;
        float g1 = expf(logit[i1] - m) / denom;
        float inv = 1.f / (g0 + g1 + 1e-20f);
        eids[n] = i0 | (i1 << 16);
        gw[n] = make_float2(g0 * inv, g1 * inv);
    }
}

// ---------------- router pass 2: hierarchical list build (256 global atomics total) ----------------
__global__ __launch_bounds__(128) void build_lists(
    const int* __restrict__ eids, const float2* __restrict__ gw,
    int* __restrict__ cnt, int* __restrict__ tok, float* __restrict__ wgt)
{
    __shared__ int lcnt[NE];
    __shared__ int gbase[NE];
    int t = threadIdx.x;                  // 0..127, one token each
    int n = blockIdx.x * 128 + t;
    if (t < NE) lcnt[t] = 0;
    __syncthreads();
    int packed = eids[n];
    float2 w = gw[n];
    int e0 = packed & 0xffff, e1 = packed >> 16;
    int s0 = atomicAdd(&lcnt[e0], 1);     // LDS atomics: cheap, block-local
    int s1 = atomicAdd(&lcnt[e1], 1);
    __syncthreads();
    if (t < NE) gbase[t] = atomicAdd(&cnt[t], lcnt[t]);   // 8 global atomics per block
    __syncthreads();
    int p0 = gbase[e0] + s0, p1 = gbase[e1] + s1;
    tok[e0 * NTOK + p0] = n; wgt[e0 * NTOK + p0] = w.x;
    tok[e1 * NTOK + p1] = n; wgt[e1 * NTOK + p1] = w.y;
}

__global__ void prefix_kernel(const int* __restrict__ cnt, int* __restrict__ pfx)
{
    if (threadIdx.x == 0) {
        int s = 0;
        for (int e = 0; e < NE; e++) { pfx[e] = s; s += cnt[e]; }
        pfx[NE] = s;
    }
}

// ---------------- GEMM1: act = silu(A@W1) * (A@W3), bf16 out ----------------
// A rows gathered via tok list (or identity when tok==nullptr).
// W1t/W3t are [e][Hdim][DM] (n-major, k-contiguous).
__global__ __launch_bounds__(256) void gemm1_swiglu(
    const bf16* __restrict__ xb,
    const bf16* __restrict__ W1t, const bf16* __restrict__ W3t,
    bf16* __restrict__ act,
    const int* __restrict__ cnt, const int* __restrict__ pfx, const int* __restrict__ tok,
    int Hdim)
{
    int e = blockIdx.z;
    int count = cnt ? cnt[e] : NTOK;
    int m0 = blockIdx.y * 64;
    if (m0 >= count) return;
    int h0 = blockIdx.x * 64;
    int base = pfx ? pfx[e] : 0;
    const bf16* B1 = W1t + (size_t)e * Hdim * DM;
    const bf16* B3 = W3t + (size_t)e * Hdim * DM;
    const int* tlist = tok ? tok + e * NTOK : nullptr;

    __shared__ bf16 As[64][40];
    __shared__ bf16 Bs1[64][40];
    __shared__ bf16 Bs3[64][40];

    int tid  = threadIdx.x;
    int lrow = tid >> 2;          // 0..63
    int lcol = (tid & 3) * 8;     // 0,8,16,24

    int slot = m0 + lrow;
    int rowIdx;
    if (tlist) rowIdx = (slot < count) ? tlist[slot] : 0;
    else       rowIdx = (slot < count) ? slot : 0;
    const bf16* aPtr  = xb + (size_t)rowIdx * DM + lcol;
    const bf16* b1Ptr = B1 + (size_t)(h0 + lrow) * DM + lcol;
    const bf16* b3Ptr = B3 + (size_t)(h0 + lrow) * DM + lcol;

    int wv = tid >> 6, lane = tid & 63;
    int lm = lane & 15, lk = (lane >> 4) * 8;

    f32x4 acch[4], accg[4];
    #pragma unroll
    for (int c = 0; c < 4; c++) {
        acch[c] = (f32x4){0.f, 0.f, 0.f, 0.f};
        accg[c] = (f32x4){0.f, 0.f, 0.f, 0.f};
    }

    for (int k0 = 0; k0 < DM; k0 += 32) {
        *(uint4*)&As[lrow][lcol]  = *(const uint4*)(aPtr + k0);
        *(uint4*)&Bs1[lrow][lcol] = *(const uint4*)(b1Ptr + k0);
        *(uint4*)&Bs3[lrow][lcol] = *(const uint4*)(b3Ptr + k0);
        __syncthreads();
        bf16x8 af = *(const bf16x8*)&As[wv * 16 + lm][lk];
        #pragma unroll
        for (int c = 0; c < 4; c++) {
            bf16x8 b1f = *(const bf16x8*)&Bs1[c * 16 + lm][lk];
            bf16x8 b3f = *(const bf16x8*)&Bs3[c * 16 + lm][lk];
            acch[c] = __builtin_amdgcn_mfma_f32_16x16x32_bf16(af, b1f, acch[c], 0, 0, 0);
            accg[c] = __builtin_amdgcn_mfma_f32_16x16x32_bf16(af, b3f, accg[c], 0, 0, 0);
        }
        __syncthreads();
    }

    #pragma unroll
    for (int c = 0; c < 4; c++) {
        #pragma unroll
        for (int r = 0; r < 4; r++) {
            int row = wv * 16 + (lane >> 4) * 4 + r;   // slot-local (MFMA C/D: row=quad*4+reg)
            int s2 = m0 + row;
            if (s2 < count) {
                float hv = acch[c][r], gv = accg[c][r];
                float a = hv / (1.f + expf(-hv)) * gv;
                act[(size_t)(base + s2) * Hdim + h0 + c * 16 + lm] = (bf16)a;
            }
        }
    }
}

// ---------------- GEMM2: out = act @ W2 (+ gate, scatter) ----------------
// W2t is [e][DM][Hdim] (n-major, k-contiguous).
__global__ __launch_bounds__(256) void gemm2_combine(
    const bf16* __restrict__ act,
    const bf16* __restrict__ W2t,
    float* __restrict__ out,
    const int* __restrict__ cnt, const int* __restrict__ pfx,
    const int* __restrict__ tok, const float* __restrict__ wgt,
    int Hdim, int atomic_mode)
{
    int e = blockIdx.z;
    int count = cnt ? cnt[e] : NTOK;
    int m0 = blockIdx.y * 64;
    if (m0 >= count) return;
    int d0 = blockIdx.x * 64;
    int base = pfx ? pfx[e] : 0;
    const bf16* B = W2t + (size_t)e * DM * Hdim;

    __shared__ bf16 As[64][40];
    __shared__ bf16 Bs[64][40];

    int tid  = threadIdx.x;
    int lrow = tid >> 2;
    int lcol = (tid & 3) * 8;

    int slot = m0 + lrow;
    int arow = (slot < count) ? (base + slot) : base;   // clamp: garbage rows masked in epilogue
    const bf16* aPtr = act + (size_t)arow * Hdim + lcol;
    const bf16* bPtr = B + (size_t)(d0 + lrow) * Hdim + lcol;

    int wv = tid >> 6, lane = tid & 63;
    int lm = lane & 15, lk = (lane >> 4) * 8;

    f32x4 acc[4];
    #pragma unroll
    for (int c = 0; c < 4; c++) acc[c] = (f32x4){0.f, 0.f, 0.f, 0.f};

    for (int k0 = 0; k0 < Hdim; k0 += 32) {
        *(uint4*)&As[lrow][lcol] = *(const uint4*)(aPtr + k0);
        *(uint4*)&Bs[lrow][lcol] = *(const uint4*)(bPtr + k0);
        __syncthreads();
        bf16x8 af = *(const bf16x8*)&As[wv * 16 + lm][lk];
        #pragma unroll
        for (int c = 0; c < 4; c++) {
            bf16x8 bf_ = *(const bf16x8*)&Bs[c * 16 + lm][lk];
            acc[c] = __builtin_amdgcn_mfma_f32_16x16x32_bf16(af, bf_, acc[c], 0, 0, 0);
        }
        __syncthreads();
    }

    #pragma unroll
    for (int c = 0; c < 4; c++) {
        #pragma unroll
        for (int r = 0; r < 4; r++) {
            int row = wv * 16 + (lane >> 4) * 4 + r;
            int s2 = m0 + row;
            if (s2 < count) {
                int col = d0 + c * 16 + lm;
                float v = acc[c][r];
                if (atomic_mode) {
                    int t = tok[e * NTOK + s2];
                    float w = wgt[e * NTOK + s2];
                    atomicAdd(&out[(size_t)t * DM + col], w * v);
                } else {
                    out[(size_t)s2 * DM + col] = v;
                }
            }
        }
    }
}

extern "C" void kernel_launch(void* const* d_in, const int* in_sizes, int n_in,
                              void* d_out, int out_size, void* d_ws, size_t ws_size,
                              hipStream_t stream)
{
    const float* x   = (const float*)d_in[0];
    const float* Wg  = (const float*)d_in[1];
    const float* W1  = (const float*)d_in[2];
    const float* W3  = (const float*)d_in[3];
    const float* W2  = (const float*)d_in[4];
    const float* Ws1 = (const float*)d_in[5];
    const float* Ws3 = (const float*)d_in[6];
    const float* Ws2 = (const float*)d_in[7];
    float* out = (float*)d_out;
    char*  ws  = (char*)d_ws;

    int*    cnt  = (int*)(ws + OFF_CNT);
    int*    pfx  = (int*)(ws + OFF_CNT + 32);
    int*    tok  = (int*)(ws + OFF_TOK);
    float*  wgt  = (float*)(ws + OFF_WGT);
    bf16*   xb   = (bf16*)(ws + OFF_XB);
    bf16*   w1t  = (bf16*)(ws + OFF_W1T);
    bf16*   w3t  = (bf16*)(ws + OFF_W3T);
    bf16*   w2t  = (bf16*)(ws + OFF_W2T);
    bf16*   ws1t = (bf16*)(ws + OFF_WS1T);
    bf16*   ws3t = (bf16*)(ws + OFF_WS3T);
    bf16*   ws2t = (bf16*)(ws + OFF_WS2T);
    bf16*   actr = (bf16*)(ws + OFF_ACTR);
    bf16*   acts = (bf16*)(ws + OFF_ACTS);
    int*    eids = (int*)(ws + OFF_EIDS);
    float2* gw   = (float2*)(ws + OFF_GW);

    hipMemsetAsync(ws, 0, 256, stream);

    cvt_x_kernel<<<4096, 256, 0, stream>>>(x, xb, NTOK * DM / 4);

    // weights -> bf16, transposed to [n][k]
    transpose_cvt<<<dim3(22, 32, 8), 256, 0, stream>>>(W1,  w1t,  1024, 704);
    transpose_cvt<<<dim3(22, 32, 8), 256, 0, stream>>>(W3,  w3t,  1024, 704);
    transpose_cvt<<<dim3(32, 22, 8), 256, 0, stream>>>(W2,  w2t,  704, 1024);
    transpose_cvt<<<dim3(44, 32, 1), 256, 0, stream>>>(Ws1, ws1t, 1024, 1408);
    transpose_cvt<<<dim3(44, 32, 1), 256, 0, stream>>>(Ws3, ws3t, 1024, 1408);
    transpose_cvt<<<dim3(32, 44, 1), 256, 0, stream>>>(Ws2, ws2t, 1408, 1024);

    router_logits<<<1024, 256, 0, stream>>>(x, Wg, eids, gw);
    build_lists<<<32, 128, 0, stream>>>(eids, gw, cnt, tok, wgt);
    prefix_kernel<<<1, 64, 0, stream>>>(cnt, pfx);

    // routed expert up-proj + swiglu
    gemm1_swiglu<<<dim3(HE / 64, 64, NE), 256, 0, stream>>>(xb, w1t, w3t, actr, cnt, pfx, tok, HE);
    // shared expert up-proj + swiglu
    gemm1_swiglu<<<dim3(HS / 64, 64, 1), 256, 0, stream>>>(xb, ws1t, ws3t, acts, nullptr, nullptr, nullptr, HS);
    // shared expert down-proj: dense write of out (covers every element)
    gemm2_combine<<<dim3(DM / 64, 64, 1), 256, 0, stream>>>(acts, ws2t, out, nullptr, nullptr, nullptr, nullptr, HS, 0);
    // routed down-proj: gate-weighted atomic accumulate on top
    gemm2_combine<<<dim3(DM / 64, 64, NE), 256, 0, stream>>>(actr, w2t, out, cnt, pfx, tok, wgt, HE, 1);
}

// Round 3
// 367.474 us; speedup vs baseline: 1.2648x; 1.0367x over previous
//
#include <hip/hip_runtime.h>
#include <math.h>

typedef __bf16 bf16;
typedef __attribute__((ext_vector_type(8))) __bf16 bf16x8;
typedef __attribute__((ext_vector_type(4))) __bf16 bf16x4;
typedef __attribute__((ext_vector_type(4))) float f32x4;

#define NTOK 4096
#define DM   1024
#define NE   8
#define HE   704
#define HS   1408

// ---------------- workspace layout (bytes) ----------------
#define OFF_CNT   0u            // 8 ints, pfx[9] at +32
#define OFF_TOK   256u          // 8*4096 ints
#define OFF_WGT   131328u       // 8*4096 floats
#define OFF_XB    262400u       // 4096*1024 bf16
#define OFF_W1T   8651008u      // [E][HE][DM] bf16
#define OFF_W3T   20185344u
#define OFF_W2T   31719680u     // [E][DM][HE] bf16
#define OFF_WS1T  43254016u     // [HS][DM] bf16
#define OFF_WS3T  46137600u
#define OFF_WS2T  49021184u     // [DM][HS] bf16
#define OFF_ACTR  51904768u     // [8192][HE] bf16 (compacted by prefix sum)
#define OFF_ACTS  63439104u     // [NTOK][HS] bf16
#define OFF_EIDS  74973440u     // [NTOK] int (e0 | e1<<16)
#define OFF_GW    74989824u     // [NTOK] float2 (w0, w1)
// end: 75022592 (~71.6 MB)

// async global->LDS, 16 B/lane. LDS dest is wave-uniform base + lane*16 (m104/m108):
// LDS layout MUST be contiguous in lane order. Global address is per-lane (gather OK).
__device__ __forceinline__ void async_cp16(const bf16* g, bf16* l)
{
    __builtin_amdgcn_global_load_lds(
        (const __attribute__((address_space(1))) unsigned int*)g,
        (__attribute__((address_space(3))) unsigned int*)l, 16, 0, 0);
}

// ---------------- x -> bf16 ----------------
__global__ void cvt_x_kernel(const float* __restrict__ x, bf16* __restrict__ xb, int n4)
{
    int i = blockIdx.x * blockDim.x + threadIdx.x;
    if (i >= n4) return;
    float4 v = ((const float4*)x)[i];
    bf16x4 o;
    o[0] = (bf16)v.x; o[1] = (bf16)v.y; o[2] = (bf16)v.z; o[3] = (bf16)v.w;
    ((bf16x4*)xb)[i] = o;
}

// ---------------- transpose + convert: src [R][C] f32 -> dst [C][R] bf16 ----------------
__global__ void transpose_cvt(const float* __restrict__ src, bf16* __restrict__ dst, int R, int C)
{
    __shared__ float t[32][33];
    int c0 = blockIdx.x * 32, r0 = blockIdx.y * 32;
    size_t base = (size_t)blockIdx.z * (size_t)R * (size_t)C;
    src += base; dst += base;
    int row  = threadIdx.x >> 3;        // 0..31
    int col4 = (threadIdx.x & 7) * 4;   // 0..28
    float4 v = *(const float4*)&src[(size_t)(r0 + row) * C + c0 + col4];
    t[row][col4 + 0] = v.x; t[row][col4 + 1] = v.y;
    t[row][col4 + 2] = v.z; t[row][col4 + 3] = v.w;
    __syncthreads();
    bf16x4 o;
    o[0] = (bf16)t[col4 + 0][row];
    o[1] = (bf16)t[col4 + 1][row];
    o[2] = (bf16)t[col4 + 2][row];
    o[3] = (bf16)t[col4 + 3][row];
    *(bf16x4*)&dst[(size_t)(c0 + row) * R + r0 + col4] = o;
}

// ---------------- router pass 1: fp32 logits, softmax, top-2 per token ----------------
__global__ __launch_bounds__(256) void router_logits(
    const float* __restrict__ x, const float* __restrict__ Wg,
    int* __restrict__ eids, float2* __restrict__ gw)
{
    int n    = blockIdx.x * 4 + (threadIdx.x >> 6);   // wave per token
    int lane = threadIdx.x & 63;
    const float* xrow = x + (size_t)n * DM;
    float xr[16];
    #pragma unroll
    for (int j = 0; j < 16; j++) xr[j] = xrow[lane + 64 * j];
    float logit[NE];
    #pragma unroll
    for (int e = 0; e < NE; e++) {
        const float* wr = Wg + e * DM;
        float s = 0.f;
        #pragma unroll
        for (int j = 0; j < 16; j++) s += xr[j] * wr[lane + 64 * j];
        #pragma unroll
        for (int off = 32; off; off >>= 1) s += __shfl_xor(s, off, 64);
        logit[e] = s;
    }
    if (lane == 0) {
        int i0 = 0;
        #pragma unroll
        for (int e = 1; e < NE; e++) if (logit[e] > logit[i0]) i0 = e;
        int i1 = (i0 == 0) ? 1 : 0;
        #pragma unroll
        for (int e = 0; e < NE; e++) if (e != i0 && logit[e] > logit[i1]) i1 = e;
        float m = logit[0];
        #pragma unroll
        for (int e = 1; e < NE; e++) m = fmaxf(m, logit[e]);
        float denom = 0.f;
        #pragma unroll
        for (int e = 0; e < NE; e++) denom += expf(logit[e] - m);
        float g0 = expf(logit[i0] - m) / denom;
        float g1 = expf(logit[i1] - m) / denom;
        float inv = 1.f / (g0 + g1 + 1e-20f);
        eids[n] = i0 | (i1 << 16);
        gw[n] = make_float2(g0 * inv, g1 * inv);
    }
}

// ---------------- router pass 2: hierarchical list build ----------------
__global__ __launch_bounds__(128) void build_lists(
    const int* __restrict__ eids, const float2* __restrict__ gw,
    int* __restrict__ cnt, int* __restrict__ tok, float* __restrict__ wgt)
{
    __shared__ int lcnt[NE];
    __shared__ int gbase[NE];
    int t = threadIdx.x;
    int n = blockIdx.x * 128 + t;
    if (t < NE) lcnt[t] = 0;
    __syncthreads();
    int packed = eids[n];
    float2 w = gw[n];
    int e0 = packed & 0xffff, e1 = packed >> 16;
    int s0 = atomicAdd(&lcnt[e0], 1);
    int s1 = atomicAdd(&lcnt[e1], 1);
    __syncthreads();
    if (t < NE) gbase[t] = atomicAdd(&cnt[t], lcnt[t]);
    __syncthreads();
    int p0 = gbase[e0] + s0, p1 = gbase[e1] + s1;
    tok[e0 * NTOK + p0] = n; wgt[e0 * NTOK + p0] = w.x;
    tok[e1 * NTOK + p1] = n; wgt[e1 * NTOK + p1] = w.y;
}

__global__ void prefix_kernel(const int* __restrict__ cnt, int* __restrict__ pfx)
{
    if (threadIdx.x == 0) {
        int s = 0;
        for (int e = 0; e < NE; e++) { pfx[e] = s; s += cnt[e]; }
        pfx[NE] = s;
    }
}

// ---------------- GEMM1: act = silu(A@W1) * (A@W3), bf16 out ----------------
// Tile 128(m) x 64(h), BK=32. Per wave: 64x32 per accumulator (h and g).
// LDS: As[128][32], B1s[64][32], B3s[64][32] unpadded (global_load_lds lane order).
__global__ __launch_bounds__(256) void gemm1_swiglu(
    const bf16* __restrict__ xb,
    const bf16* __restrict__ W1t, const bf16* __restrict__ W3t,
    bf16* __restrict__ act,
    const int* __restrict__ cnt, const int* __restrict__ pfx, const int* __restrict__ tok,
    int Hdim)
{
    int e = blockIdx.z;
    int count = cnt ? cnt[e] : NTOK;
    int m0 = blockIdx.y * 128;
    if (m0 >= count) return;
    int h0 = blockIdx.x * 64;
    int base = pfx ? pfx[e] : 0;
    const bf16* B1 = W1t + (size_t)e * Hdim * DM;
    const bf16* B3 = W3t + (size_t)e * Hdim * DM;
    const int* tlist = tok ? tok + e * NTOK : nullptr;

    __shared__ bf16 As[128 * 32];
    __shared__ bf16 B1s[64 * 32];
    __shared__ bf16 B3s[64 * 32];

    int tid = threadIdx.x, w = tid >> 6, lane = tid & 63;
    int lrow4 = lane >> 2;           // 0..15
    int lcol8 = (lane & 3) * 8;

    // A staging: 2 insts/wave covering rows 32w..32w+31 (gathered)
    int sA0 = m0 + 32 * w + lrow4;
    int sA1 = sA0 + 16;
    int rA0 = tlist ? (sA0 < count ? tlist[sA0] : 0) : (sA0 < count ? sA0 : 0);
    int rA1 = tlist ? (sA1 < count ? tlist[sA1] : 0) : (sA1 < count ? sA1 : 0);
    const bf16* ga0 = xb + (size_t)rA0 * DM + lcol8;
    const bf16* ga1 = xb + (size_t)rA1 * DM + lcol8;
    // B staging: 1 inst/wave each, rows 16w..16w+15 of the h-tile
    const bf16* gb1 = B1 + (size_t)(h0 + 16 * w + lrow4) * DM + lcol8;
    const bf16* gb3 = B3 + (size_t)(h0 + 16 * w + lrow4) * DM + lcol8;
    bf16* lA0 = As + 1024 * w;
    bf16* lA1 = As + 1024 * w + 512;
    bf16* lB1 = B1s + 512 * w;
    bf16* lB3 = B3s + 512 * w;

    int wm = (w & 1) * 64, wn = (w >> 1) * 32;
    int lm = lane & 15, lk = (lane >> 4) * 8;

    f32x4 acch[4][2], accg[4][2];
    #pragma unroll
    for (int i = 0; i < 4; i++)
        #pragma unroll
        for (int j = 0; j < 2; j++) {
            acch[i][j] = (f32x4){0.f, 0.f, 0.f, 0.f};
            accg[i][j] = (f32x4){0.f, 0.f, 0.f, 0.f};
        }

    for (int k0 = 0; k0 < DM; k0 += 32) {
        async_cp16(ga0, lA0);
        async_cp16(ga1, lA1);
        async_cp16(gb1, lB1);
        async_cp16(gb3, lB3);
        ga0 += 32; ga1 += 32; gb1 += 32; gb3 += 32;
        __syncthreads();
        bf16x8 af[4], b1f[2], b3f[2];
        #pragma unroll
        for (int i = 0; i < 4; i++) af[i] = *(const bf16x8*)&As[(wm + i * 16 + lm) * 32 + lk];
        #pragma unroll
        for (int j = 0; j < 2; j++) {
            b1f[j] = *(const bf16x8*)&B1s[(wn + j * 16 + lm) * 32 + lk];
            b3f[j] = *(const bf16x8*)&B3s[(wn + j * 16 + lm) * 32 + lk];
        }
        #pragma unroll
        for (int i = 0; i < 4; i++)
            #pragma unroll
            for (int j = 0; j < 2; j++) {
                acch[i][j] = __builtin_amdgcn_mfma_f32_16x16x32_bf16(af[i], b1f[j], acch[i][j], 0, 0, 0);
                accg[i][j] = __builtin_amdgcn_mfma_f32_16x16x32_bf16(af[i], b3f[j], accg[i][j], 0, 0, 0);
            }
        __syncthreads();
    }

    int quad = lane >> 4;
    #pragma unroll
    for (int i = 0; i < 4; i++)
        #pragma unroll
        for (int j = 0; j < 2; j++)
            #pragma unroll
            for (int r = 0; r < 4; r++) {
                int row = wm + i * 16 + quad * 4 + r;     // C/D: row=quad*4+reg
                int s2 = m0 + row;
                if (s2 < count) {
                    float hv = acch[i][j][r], gv = accg[i][j][r];
                    float a = hv / (1.f + expf(-hv)) * gv;
                    act[(size_t)(base + s2) * Hdim + h0 + wn + j * 16 + lm] = (bf16)a;
                }
            }
}

// ---------------- GEMM2: out = act @ W2 (+ gate, scatter) ----------------
// Tile 128(m) x 128(d), BK=32 — m97 structure. W2t is [e][DM][Hdim].
__global__ __launch_bounds__(256) void gemm2_combine(
    const bf16* __restrict__ act,
    const bf16* __restrict__ W2t,
    float* __restrict__ out,
    const int* __restrict__ cnt, const int* __restrict__ pfx,
    const int* __restrict__ tok, const float* __restrict__ wgt,
    int Hdim, int atomic_mode)
{
    int e = blockIdx.z;
    int count = cnt ? cnt[e] : NTOK;
    int m0 = blockIdx.y * 128;
    if (m0 >= count) return;
    int d0 = blockIdx.x * 128;
    int base = pfx ? pfx[e] : 0;
    const bf16* B = W2t + (size_t)e * DM * Hdim;

    __shared__ bf16 As[128 * 32];
    __shared__ bf16 Bs[128 * 32];

    int tid = threadIdx.x, w = tid >> 6, lane = tid & 63;
    int lrow4 = lane >> 2;
    int lcol8 = (lane & 3) * 8;

    int sA0 = m0 + 32 * w + lrow4;
    int sA1 = sA0 + 16;
    int arow0 = (sA0 < count) ? (base + sA0) : base;
    int arow1 = (sA1 < count) ? (base + sA1) : base;
    const bf16* ga0 = act + (size_t)arow0 * Hdim + lcol8;
    const bf16* ga1 = act + (size_t)arow1 * Hdim + lcol8;
    const bf16* gb0 = B + (size_t)(d0 + 32 * w + lrow4) * Hdim + lcol8;
    const bf16* gb1 = gb0 + (size_t)16 * Hdim;
    bf16* lA0 = As + 1024 * w;
    bf16* lA1 = As + 1024 * w + 512;
    bf16* lB0 = Bs + 1024 * w;
    bf16* lB1 = Bs + 1024 * w + 512;

    int wm = (w & 1) * 64, wn = (w >> 1) * 64;
    int lm = lane & 15, lk = (lane >> 4) * 8;

    f32x4 acc[4][4];
    #pragma unroll
    for (int i = 0; i < 4; i++)
        #pragma unroll
        for (int j = 0; j < 4; j++) acc[i][j] = (f32x4){0.f, 0.f, 0.f, 0.f};

    for (int k0 = 0; k0 < Hdim; k0 += 32) {
        async_cp16(ga0, lA0);
        async_cp16(ga1, lA1);
        async_cp16(gb0, lB0);
        async_cp16(gb1, lB1);
        ga0 += 32; ga1 += 32; gb0 += 32; gb1 += 32;
        __syncthreads();
        bf16x8 af[4], bf_[4];
        #pragma unroll
        for (int i = 0; i < 4; i++) af[i]  = *(const bf16x8*)&As[(wm + i * 16 + lm) * 32 + lk];
        #pragma unroll
        for (int j = 0; j < 4; j++) bf_[j] = *(const bf16x8*)&Bs[(wn + j * 16 + lm) * 32 + lk];
        #pragma unroll
        for (int i = 0; i < 4; i++)
            #pragma unroll
            for (int j = 0; j < 4; j++)
                acc[i][j] = __builtin_amdgcn_mfma_f32_16x16x32_bf16(af[i], bf_[j], acc[i][j], 0, 0, 0);
        __syncthreads();
    }

    int quad = lane >> 4;
    #pragma unroll
    for (int i = 0; i < 4; i++)
        #pragma unroll
        for (int j = 0; j < 4; j++)
            #pragma unroll
            for (int r = 0; r < 4; r++) {
                int row = wm + i * 16 + quad * 4 + r;
                int s2 = m0 + row;
                if (s2 < count) {
                    int col = d0 + wn + j * 16 + lm;
                    float v = acc[i][j][r];
                    if (atomic_mode) {
                        int t = tok[e * NTOK + s2];
                        float wt = wgt[e * NTOK + s2];
                        atomicAdd(&out[(size_t)t * DM + col], wt * v);
                    } else {
                        out[(size_t)s2 * DM + col] = v;
                    }
                }
            }
}

extern "C" void kernel_launch(void* const* d_in, const int* in_sizes, int n_in,
                              void* d_out, int out_size, void* d_ws, size_t ws_size,
                              hipStream_t stream)
{
    const float* x   = (const float*)d_in[0];
    const float* Wg  = (const float*)d_in[1];
    const float* W1  = (const float*)d_in[2];
    const float* W3  = (const float*)d_in[3];
    const float* W2  = (const float*)d_in[4];
    const float* Ws1 = (const float*)d_in[5];
    const float* Ws3 = (const float*)d_in[6];
    const float* Ws2 = (const float*)d_in[7];
    float* out = (float*)d_out;
    char*  ws  = (char*)d_ws;

    int*    cnt  = (int*)(ws + OFF_CNT);
    int*    pfx  = (int*)(ws + OFF_CNT + 32);
    int*    tok  = (int*)(ws + OFF_TOK);
    float*  wgt  = (float*)(ws + OFF_WGT);
    bf16*   xb   = (bf16*)(ws + OFF_XB);
    bf16*   w1t  = (bf16*)(ws + OFF_W1T);
    bf16*   w3t  = (bf16*)(ws + OFF_W3T);
    bf16*   w2t  = (bf16*)(ws + OFF_W2T);
    bf16*   ws1t = (bf16*)(ws + OFF_WS1T);
    bf16*   ws3t = (bf16*)(ws + OFF_WS3T);
    bf16*   ws2t = (bf16*)(ws + OFF_WS2T);
    bf16*   actr = (bf16*)(ws + OFF_ACTR);
    bf16*   acts = (bf16*)(ws + OFF_ACTS);
    int*    eids = (int*)(ws + OFF_EIDS);
    float2* gw   = (float2*)(ws + OFF_GW);

    hipMemsetAsync(ws, 0, 256, stream);

    cvt_x_kernel<<<4096, 256, 0, stream>>>(x, xb, NTOK * DM / 4);

    // weights -> bf16, transposed to [n][k]
    transpose_cvt<<<dim3(22, 32, 8), 256, 0, stream>>>(W1,  w1t,  1024, 704);
    transpose_cvt<<<dim3(22, 32, 8), 256, 0, stream>>>(W3,  w3t,  1024, 704);
    transpose_cvt<<<dim3(32, 22, 8), 256, 0, stream>>>(W2,  w2t,  704, 1024);
    transpose_cvt<<<dim3(44, 32, 1), 256, 0, stream>>>(Ws1, ws1t, 1024, 1408);
    transpose_cvt<<<dim3(44, 32, 1), 256, 0, stream>>>(Ws3, ws3t, 1024, 1408);
    transpose_cvt<<<dim3(32, 44, 1), 256, 0, stream>>>(Ws2, ws2t, 1408, 1024);

    router_logits<<<1024, 256, 0, stream>>>(x, Wg, eids, gw);
    build_lists<<<32, 128, 0, stream>>>(eids, gw, cnt, tok, wgt);
    prefix_kernel<<<1, 64, 0, stream>>>(cnt, pfx);

    // routed expert up-proj + swiglu   (tile 128x64)
    gemm1_swiglu<<<dim3(HE / 64, 32, NE), 256, 0, stream>>>(xb, w1t, w3t, actr, cnt, pfx, tok, HE);
    // shared expert up-proj + swiglu
    gemm1_swiglu<<<dim3(HS / 64, 32, 1), 256, 0, stream>>>(xb, ws1t, ws3t, acts, nullptr, nullptr, nullptr, HS);
    // shared expert down-proj: dense write of out (tile 128x128)
    gemm2_combine<<<dim3(DM / 128, 32, 1), 256, 0, stream>>>(acts, ws2t, out, nullptr, nullptr, nullptr, nullptr, HS, 0);
    // routed down-proj: gate-weighted atomic accumulate on top
    gemm2_combine<<<dim3(DM / 128, 32, NE), 256, 0, stream>>>(actr, w2t, out, cnt, pfx, tok, wgt, HE, 1);
}